// Round 6
// baseline (1401.831 us; speedup 1.0000x reference)
//
#include <hip/hip_runtime.h>
#include <math.h>

#define BATCH 4
#define NPTS 4096
#define KNN 16
#define DPTS 64
#define DM 128

typedef __attribute__((ext_vector_type(8))) short short8;
typedef __attribute__((ext_vector_type(4))) float floatx4;
typedef __attribute__((ext_vector_type(4))) unsigned int uintx4;

static __device__ __forceinline__ float bf2f(unsigned short h) {
    union { unsigned int u; float f; } c; c.u = ((unsigned int)h) << 16; return c.f;
}
static __device__ __forceinline__ unsigned short f2bf(float f) {
    union { float f; unsigned int u; } c; c.f = f;
    unsigned int u = c.u;
    u += 0x7fffu + ((u >> 16) & 1u);   // RNE
    return (unsigned short)(u >> 16);
}

// ---------------- kNN: bit-exact f32 expanded-form distances (matches np f32 ref), ----------------
// ---------------- top-16 with stable index tiebreak ----------------
__global__ __launch_bounds__(256) void knn_kernel(const float* __restrict__ xyz,
                                                  int* __restrict__ knn_idx) {
    extern __shared__ char smem[];
    float* sx  = (float*)smem;                       // 4096*3 f32 = 48 KB
    float* ssq = (float*)(smem + 49152);             // 4096 f32 = 16 KB
    float* md  = (float*)(smem + 65536);             // [64][4][16] f32 = 16 KB
    int*   mi  = (int*)(smem + 81920);               // [64][4][16] int = 16 KB

    int b = blockIdx.x >> 6;              // 64 blocks per batch
    int qbase = (blockIdx.x & 63) * 64;   // 64 queries per block
    const float* bx = xyz + b * NPTS * 3;
    for (int t = threadIdx.x; t < NPTS * 3 / 4; t += 256)
        ((float4*)sx)[t] = ((const float4*)bx)[t];
    __syncthreads();
    // sq[j] = ((x*x + y*y) + z*z) sequential f32, no FMA — bit-exact vs numpy f32
    for (int j = threadIdx.x; j < NPTS; j += 256) {
        float x = sx[j*3+0], y = sx[j*3+1], z = sx[j*3+2];
        ssq[j] = __fadd_rn(__fadd_rn(__fmul_rn(x, x), __fmul_rn(y, y)), __fmul_rn(z, z));
    }
    __syncthreads();

    int q = qbase + (threadIdx.x >> 2);
    int s = threadIdx.x & 3;
    float qx = sx[q*3+0], qy = sx[q*3+1], qz = sx[q*3+2];
    float qsq = ssq[q];
    float bd[16]; int bi[16];
    #pragma unroll
    for (int t = 0; t < 16; ++t) { bd[t] = 3.0e38f; bi[t] = 0; }
    int j0 = s * 1024;
    for (int m = 0; m < 1024; ++m) {
        int j = j0 + m;
        // dot = ((xq*xj + yq*yj) + zq*zj) sequential f32, no FMA
        float dot = __fadd_rn(__fadd_rn(__fmul_rn(qx, sx[j*3+0]), __fmul_rn(qy, sx[j*3+1])),
                              __fmul_rn(qz, sx[j*3+2]));
        // d2 = (sq_q + sq_j) - 2*dot, matching np broadcast-add then subtract
        float d = __fsub_rn(__fadd_rn(qsq, ssq[j]), __fmul_rn(2.0f, dot));
        if (d < bd[15]) {   // strict <: equal-d later-index loses, matching top_k
            int pos = 15;
            #pragma unroll
            for (int t = 14; t >= 0; --t) if (bd[t] > d) pos = t;
            #pragma unroll
            for (int t = 15; t > 0; --t) {
                bool mv = (t > pos);
                bd[t] = mv ? bd[t-1] : bd[t];
                bi[t] = mv ? bi[t-1] : bi[t];
            }
            #pragma unroll
            for (int t = 0; t < 16; ++t) if (t == pos) { bd[t] = d; bi[t] = j; }
        }
    }
    int lq = threadIdx.x >> 2;
    #pragma unroll
    for (int t = 0; t < 16; ++t) { md[(lq*4+s)*16+t] = bd[t]; mi[(lq*4+s)*16+t] = bi[t]; }
    __syncthreads();
    if (s == 0) {
        int p0=0,p1=0,p2=0,p3=0;
        int out_base = (b*NPTS + q) * KNN;
        #pragma unroll
        for (int t = 0; t < 16; ++t) {
            float d0 = md[(lq*4+0)*16+p0]; int i0 = mi[(lq*4+0)*16+p0];
            float d1 = md[(lq*4+1)*16+p1]; int i1 = mi[(lq*4+1)*16+p1];
            float d2 = md[(lq*4+2)*16+p2]; int i2 = mi[(lq*4+2)*16+p2];
            float d3 = md[(lq*4+3)*16+p3]; int i3 = mi[(lq*4+3)*16+p3];
            float bdv = d0; int bii = i0; int which = 0;
            if (d1 < bdv || (d1 == bdv && i1 < bii)) { bdv=d1; bii=i1; which=1; }
            if (d2 < bdv || (d2 == bdv && i2 < bii)) { bdv=d2; bii=i2; which=2; }
            if (d3 < bdv || (d3 == bdv && i3 < bii)) { bdv=d3; bii=i3; which=3; }
            knn_idx[out_base + t] = bii;
            if (which==0) p0++; else if (which==1) p1++; else if (which==2) p2++; else p3++;
        }
    }
}

// ---------------- pack w_d2 / w_g1 / w_g2 into MFMA B-fragment layout (bf16) ----------------
// layout: [g][kt][nt][lane][i]  value = w[kt*32 + (lane>>4)*8 + i][nt*16 + (lane&15)]
__global__ __launch_bounds__(256) void pack_kernel(const float* __restrict__ w_d2,
                                                   const float* __restrict__ w_g1,
                                                   const float* __restrict__ w_g2,
                                                   unsigned short* __restrict__ wpack) {
    int t = blockIdx.x * 256 + threadIdx.x;
    if (t >= 3*4*8*64) return;
    int lane = t & 63;
    int nt = (t >> 6) & 7;
    int kt = (t >> 9) & 3;
    int g  = t >> 11;
    const float* w = (g == 0) ? w_d2 : (g == 1) ? w_g1 : w_g2;
    int colbase = nt*16 + (lane & 15);
    int kbase   = kt*32 + (lane >> 4)*8;
    union { unsigned short us[8]; uintx4 v; } u;
    #pragma unroll
    for (int i = 0; i < 8; ++i) u.us[i] = f2bf(w[(kbase+i)*DM + colbase]);
    ((uintx4*)wpack)[t] = u.v;
}

// ---------------- fc1 + q/k/v projection (f32 compute, bf16 outputs) ----------------
__global__ __launch_bounds__(256) void qkv_kernel(
    const float* __restrict__ features, const float* __restrict__ w_fc1, const float* __restrict__ b_fc1,
    const float* __restrict__ w_q, const float* __restrict__ w_k, const float* __restrict__ w_v,
    unsigned short* __restrict__ qo, unsigned short* __restrict__ ko, unsigned short* __restrict__ vo) {
    extern __shared__ char smem[];
    float* sfeat = (float*)smem;                       // [64][64]  16 KB
    float* sxbuf = (float*)(smem + 16384);             // [64][128] 32 KB
    float* swt   = (float*)(smem + 16384 + 32768);     // [128][128] 64 KB
    int rowbase = blockIdx.x * 64;

    for (int t = threadIdx.x; t < 64*64/4; t += 256)
        ((float4*)sfeat)[t] = ((const float4*)(features + rowbase*DPTS))[t];
    for (int t = threadIdx.x; t < 64*DM/4; t += 256)
        ((float4*)swt)[t] = ((const float4*)w_fc1)[t];
    __syncthreads();

    int r  = threadIdx.x >> 2;
    int cg = (threadIdx.x & 3) * 32;
    {
        float acc[32];
        #pragma unroll
        for (int cc = 0; cc < 32; ++cc) acc[cc] = b_fc1[cg + cc];
        for (int h = 0; h < 64; ++h) {
            float f = sfeat[r*64 + h];
            #pragma unroll
            for (int cc = 0; cc < 32; ++cc) acc[cc] += f * swt[h*DM + cg + cc];
        }
        #pragma unroll
        for (int cc = 0; cc < 32; ++cc) sxbuf[r*DM + cg + cc] = acc[cc];
    }
    __syncthreads();

    for (int g = 0; g < 3; ++g) {
        const float* wsrc = (g == 0) ? w_q : (g == 1) ? w_k : w_v;
        unsigned short* op = ((g == 0) ? qo : (g == 1) ? ko : vo) + (rowbase + r)*DM + cg;
        for (int t = threadIdx.x; t < DM*DM/4; t += 256)
            ((float4*)swt)[t] = ((const float4*)wsrc)[t];
        __syncthreads();
        float a2[32];
        #pragma unroll
        for (int cc = 0; cc < 32; ++cc) a2[cc] = 0.f;
        for (int h = 0; h < DM; ++h) {
            float xv = sxbuf[r*DM + h];
            #pragma unroll
            for (int cc = 0; cc < 32; ++cc) a2[cc] += xv * swt[h*DM + cg + cc];
        }
        #pragma unroll
        for (int cc = 0; cc < 32; ++cc) op[cc] = f2bf(a2[cc]);
        __syncthreads();
    }
}

// ---------------- main fused per-point kernel ----------------
// one wave per point (4 pts/wave sequentially), 4 waves/block
// LDS: wpack 96 KB | w_d1 1.5 KB | biases 2 KB | per-wave {pe,a1,v bf16[16][128], rel, idx, res}
__global__ __launch_bounds__(256) void main_kernel(
    const float* __restrict__ xyz, const float* __restrict__ features,
    const float* __restrict__ w_fc2, const float* __restrict__ b_fc2,
    const float* __restrict__ w_d1, const float* __restrict__ b_d1,
    const float* __restrict__ b_d2, const float* __restrict__ b_g1, const float* __restrict__ b_g2,
    const unsigned short* __restrict__ qg, const unsigned short* __restrict__ kg,
    const unsigned short* __restrict__ vg,
    const int* __restrict__ knn_idx, const unsigned short* __restrict__ wpack,
    float* __restrict__ res_out, float* __restrict__ attn_out) {
    extern __shared__ char smem[];
    unsigned short* swp = (unsigned short*)smem;          // 98304 B
    float* sw_d1 = (float*)(smem + 98304);                // 1536 B
    float* sb_d1 = (float*)(smem + 99840);
    float* sb_d2 = (float*)(smem + 100352);
    float* sb_g1 = (float*)(smem + 100864);
    float* sb_g2 = (float*)(smem + 101376);

    for (int t = threadIdx.x; t < 98304/16; t += 256)
        ((uintx4*)swp)[t] = ((const uintx4*)wpack)[t];
    for (int t = threadIdx.x; t < 384; t += 256) sw_d1[t] = w_d1[t];
    if (threadIdx.x < 128) {
        sb_d1[threadIdx.x] = b_d1[threadIdx.x];
        sb_d2[threadIdx.x] = b_d2[threadIdx.x];
        sb_g1[threadIdx.x] = b_g1[threadIdx.x];
        sb_g2[threadIdx.x] = b_g2[threadIdx.x];
    }
    __syncthreads();

    int wave = threadIdx.x >> 6;
    int lane = threadIdx.x & 63;
    int nbr  = lane & 15;     // A-operand M index / D-output column-in-tile
    int cblk = lane >> 4;
    char* wbase = smem + 101888 + wave * 13056;
    unsigned short* pe_l = (unsigned short*)wbase;          // [16][128] bf16 swizzled
    unsigned short* a1_l = (unsigned short*)(wbase + 4096);
    unsigned short* v_l  = (unsigned short*)(wbase + 8192);
    float* rel_l = (float*)(wbase + 12288);                 // [16][3]
    int*   idx_l = (int*)(wbase + 12480);                   // [16]
    float* res_l = (float*)(wbase + 12544);                 // [128]

    const float inv_sqrt_d = 0.08838834764831845f;          // 1/sqrt(128)

    for (int pt = 0; pt < 4; ++pt) {
        int p = (blockIdx.x * 4 + wave) * 4 + pt;
        int b = p >> 12, n = p & 4095;
        int pbase = b * NPTS + n;

        // phase 0: neighbor idx + rel
        if (lane < 16) {
            int id = knn_idx[pbase*KNN + lane];
            idx_l[lane] = id;
            const float* cp = xyz + (b*NPTS + id)*3;
            const float* qp = xyz + pbase*3;
            rel_l[lane*3+0] = qp[0] - cp[0];
            rel_l[lane*3+1] = qp[1] - cp[1];
            rel_l[lane*3+2] = qp[2] - cp[2];
        }
        __syncthreads();

        int myidx = idx_l[nbr];
        // phase 1a: gather V rows -> v_l (swizzled)
        {
            const unsigned short* vp = vg + (b*NPTS + myidx)*DM;
            #pragma unroll
            for (int kt = 0; kt < 4; ++kt) {
                int c8 = kt*32 + cblk*8;
                uintx4 vr = *((const uintx4*)(vp + c8));
                int byte = (nbr*256 + c8*2) ^ ((nbr & 7) << 4);
                *(uintx4*)(( char*)v_l + byte) = vr;
            }
        }
        // phase 1b: h1 = relu(rel @ w_d1 + b_d1), A-frag layout
        short8 af[4];
        {
            float r0 = rel_l[nbr*3+0], r1 = rel_l[nbr*3+1], r2 = rel_l[nbr*3+2];
            #pragma unroll
            for (int kt = 0; kt < 4; ++kt) {
                #pragma unroll
                for (int i = 0; i < 8; ++i) {
                    int c = kt*32 + cblk*8 + i;
                    float h = r0*sw_d1[c] + r1*sw_d1[DM + c] + r2*sw_d1[2*DM + c] + sb_d1[c];
                    h = fmaxf(h, 0.f);
                    af[kt][i] = (short)f2bf(h);
                }
            }
        }
        // phase 1c: pe = h1 @ w_d2 + b_d2  (GEMM 0)
        for (int nt = 0; nt < 8; ++nt) {
            floatx4 acc = {0.f, 0.f, 0.f, 0.f};
            #pragma unroll
            for (int kt = 0; kt < 4; ++kt) {
                short8 bf = *((const short8*)(swp + ((0*4 + kt)*8 + nt)*512 + lane*8));
                acc = __builtin_amdgcn_mfma_f32_16x16x32_bf16(af[kt], bf, acc, 0, 0, 0);
            }
            int c = nt*16 + nbr;
            #pragma unroll
            for (int rg = 0; rg < 4; ++rg) {
                int krow = cblk*4 + rg;
                float pv = acc[rg] + sb_d2[c];
                int byte = (krow*256 + c*2) ^ ((krow & 7) << 4);
                *(unsigned short*)((char*)pe_l + byte) = f2bf(pv);
            }
        }
        __syncthreads();

        // phase 2: t = q - k_g + pe -> A-frags ; a1 = relu(t @ w_g1 + b_g1) (GEMM 1)
        short8 tf[4];
        {
            const unsigned short* kp = kg + (b*NPTS + myidx)*DM;
            const unsigned short* qp = qg + pbase*DM;
            #pragma unroll
            for (int kt = 0; kt < 4; ++kt) {
                int c8 = kt*32 + cblk*8;
                uintx4 kr = *((const uintx4*)(kp + c8));
                uintx4 qr = *((const uintx4*)(qp + c8));
                int byte = (nbr*256 + c8*2) ^ ((nbr & 7) << 4);
                uintx4 pr = *(const uintx4*)((char*)pe_l + byte);
                #pragma unroll
                for (int w2 = 0; w2 < 4; ++w2) {
                    float k0 = bf2f((unsigned short)(kr[w2] & 0xffffu));
                    float k1 = bf2f((unsigned short)(kr[w2] >> 16));
                    float q0 = bf2f((unsigned short)(qr[w2] & 0xffffu));
                    float q1 = bf2f((unsigned short)(qr[w2] >> 16));
                    float p0 = bf2f((unsigned short)(pr[w2] & 0xffffu));
                    float p1 = bf2f((unsigned short)(pr[w2] >> 16));
                    tf[kt][w2*2]   = (short)f2bf(q0 - k0 + p0);
                    tf[kt][w2*2+1] = (short)f2bf(q1 - k1 + p1);
                }
            }
        }
        for (int nt = 0; nt < 8; ++nt) {
            floatx4 acc = {0.f, 0.f, 0.f, 0.f};
            #pragma unroll
            for (int kt = 0; kt < 4; ++kt) {
                short8 bf = *((const short8*)(swp + ((1*4 + kt)*8 + nt)*512 + lane*8));
                acc = __builtin_amdgcn_mfma_f32_16x16x32_bf16(tf[kt], bf, acc, 0, 0, 0);
            }
            int c = nt*16 + nbr;
            #pragma unroll
            for (int rg = 0; rg < 4; ++rg) {
                int krow = cblk*4 + rg;
                float av = fmaxf(acc[rg] + sb_g1[c], 0.f);
                int byte = (krow*256 + c*2) ^ ((krow & 7) << 4);
                *(unsigned short*)((char*)a1_l + byte) = f2bf(av);
            }
        }
        __syncthreads();

        // phase 3: s = (a1 @ w_g2 + b_g2)/sqrt(D); softmax over K; attn out; res partial
        short8 a1f[4];
        #pragma unroll
        for (int kt = 0; kt < 4; ++kt) {
            int c8 = kt*32 + cblk*8;
            int byte = (nbr*256 + c8*2) ^ ((nbr & 7) << 4);
            a1f[kt] = *(const short8*)((char*)a1_l + byte);
        }
        for (int nt = 0; nt < 8; ++nt) {
            floatx4 acc = {0.f, 0.f, 0.f, 0.f};
            #pragma unroll
            for (int kt = 0; kt < 4; ++kt) {
                short8 bf = *((const short8*)(swp + ((2*4 + kt)*8 + nt)*512 + lane*8));
                acc = __builtin_amdgcn_mfma_f32_16x16x32_bf16(a1f[kt], bf, acc, 0, 0, 0);
            }
            int c = nt*16 + nbr;
            float s[4];
            #pragma unroll
            for (int rg = 0; rg < 4; ++rg) s[rg] = (acc[rg] + sb_g2[c]) * inv_sqrt_d;
            float mx = fmaxf(fmaxf(s[0], s[1]), fmaxf(s[2], s[3]));
            mx = fmaxf(mx, __shfl_xor(mx, 16));
            mx = fmaxf(mx, __shfl_xor(mx, 32));
            float e[4]; float sum = 0.f;
            #pragma unroll
            for (int rg = 0; rg < 4; ++rg) { e[rg] = __expf(s[rg] - mx); sum += e[rg]; }
            sum += __shfl_xor(sum, 16);
            sum += __shfl_xor(sum, 32);
            float inv = 1.f / sum;
            float rpart = 0.f;
            #pragma unroll
            for (int rg = 0; rg < 4; ++rg) {
                float a = e[rg] * inv;
                int krow = cblk*4 + rg;
                attn_out[(pbase*KNN + krow)*DM + c] = a;
                int byte = (krow*256 + c*2) ^ ((krow & 7) << 4);
                float vv = bf2f(*(const unsigned short*)((char*)v_l + byte));
                float pv = bf2f(*(const unsigned short*)((char*)pe_l + byte));
                rpart += a * (vv + pv);
            }
            rpart += __shfl_xor(rpart, 16);
            rpart += __shfl_xor(rpart, 32);
            if (lane < 16) res_l[nt*16 + lane] = rpart;
        }
        __syncthreads();

        // phase 4: res = res_l @ w_fc2 + b_fc2 + features
        {
            float accr = 0.f;
            #pragma unroll 4
            for (int c = 0; c < DM; ++c) accr += res_l[c] * w_fc2[c*DPTS + lane];
            res_out[pbase*DPTS + lane] = accr + b_fc2[lane] + features[pbase*DPTS + lane];
        }
        __syncthreads();
    }
}

extern "C" void kernel_launch(void* const* d_in, const int* in_sizes, int n_in,
                              void* d_out, int out_size, void* d_ws, size_t ws_size,
                              hipStream_t stream) {
    const float* xyz      = (const float*)d_in[0];
    const float* features = (const float*)d_in[1];
    const float* w_fc1    = (const float*)d_in[2];
    const float* b_fc1    = (const float*)d_in[3];
    const float* w_fc2    = (const float*)d_in[4];
    const float* b_fc2    = (const float*)d_in[5];
    const float* w_d1     = (const float*)d_in[6];
    const float* b_d1     = (const float*)d_in[7];
    const float* w_d2     = (const float*)d_in[8];
    const float* b_d2     = (const float*)d_in[9];
    const float* w_g1     = (const float*)d_in[10];
    const float* b_g1     = (const float*)d_in[11];
    const float* w_g2     = (const float*)d_in[12];
    const float* b_g2     = (const float*)d_in[13];
    const float* w_q      = (const float*)d_in[14];
    const float* w_k      = (const float*)d_in[15];
    const float* w_v      = (const float*)d_in[16];

    char* ws = (char*)d_ws;
    int* knn            = (int*)ws;                                  // 1 MB
    unsigned short* qb  = (unsigned short*)(ws + (1 << 20));         // 4 MB
    unsigned short* kb  = (unsigned short*)(ws + (5 << 20));         // 4 MB
    unsigned short* vb  = (unsigned short*)(ws + (9 << 20));         // 4 MB
    unsigned short* wpk = (unsigned short*)(ws + (13 << 20));        // 96 KB

    float* res_out  = (float*)d_out;
    float* attn_out = res_out + BATCH*NPTS*DPTS;

    pack_kernel<<<dim3(24), dim3(256), 0, stream>>>(w_d2, w_g1, w_g2, wpk);
    knn_kernel<<<dim3(256), dim3(256), 98304, stream>>>(xyz, knn);
    qkv_kernel<<<dim3(256), dim3(256), 114688, stream>>>(features, w_fc1, b_fc1,
                                                         w_q, w_k, w_v, qb, kb, vb);
    main_kernel<<<dim3(1024), dim3(256), 154112, stream>>>(
        xyz, features, w_fc2, b_fc2, w_d1, b_d1, b_d2, b_g1, b_g2,
        qb, kb, vb, knn, wpk, res_out, attn_out);
}

// Round 7
// 903.986 us; speedup vs baseline: 1.5507x; 1.5507x over previous
//
#include <hip/hip_runtime.h>
#include <math.h>

#define BATCH 4
#define NPTS 4096
#define KNN 16
#define DPTS 64
#define DM 128

typedef __attribute__((ext_vector_type(8))) short short8;
typedef __attribute__((ext_vector_type(4))) float floatx4;
typedef __attribute__((ext_vector_type(4))) unsigned int uintx4;

static __device__ __forceinline__ float bf2f(unsigned short h) {
    union { unsigned int u; float f; } c; c.u = ((unsigned int)h) << 16; return c.f;
}
static __device__ __forceinline__ unsigned short f2bf(float f) {
    union { float f; unsigned int u; } c; c.f = f;
    unsigned int u = c.u;
    u += 0x7fffu + ((u >> 16) & 1u);   // RNE
    return (unsigned short)(u >> 16);
}

// ---------------- kNN v2: bit-exact f32 expanded-form distances, register-resident top-16 ----
// Fixes vs v1 (rocprof r6: 780us, VGPR=28 -> scratch spill, 2.6e7 bank conflicts, 10.6% occ):
//  - named scalars bd0..bd15/bi0..bi15, static bubble-insert chain -> no scratch
//  - SoA coords padded +1 word per 1024 (jj=j+(j>>10)) -> 4 s-groups hit distinct banks
//  - LDS 96KB -> 72.1KB -> 2 blocks/CU
__global__ __launch_bounds__(256) void knn_kernel(const float* __restrict__ xyz,
                                                  int* __restrict__ knn_idx) {
    extern __shared__ char smem[];
    float* sxx = (float*)smem;                    // 4100 f32
    float* sxy = sxx + 4100;
    float* sxz = sxy + 4100;
    float* md  = sxz + 4100;                      // [64*4][16] f32 (16 KB)
    unsigned short* mi = (unsigned short*)(md + 4096);  // [64*4][16] u16 (8 KB)

    int b = blockIdx.x >> 6;              // 64 blocks per batch
    int qbase = (blockIdx.x & 63) * 64;   // 64 queries per block
    const float* bx = xyz + b * NPTS * 3;
    for (int j = threadIdx.x; j < NPTS; j += 256) {
        int jj = j + (j >> 10);
        sxx[jj] = bx[j*3+0];
        sxy[jj] = bx[j*3+1];
        sxz[jj] = bx[j*3+2];
    }
    __syncthreads();

    int q = qbase + (threadIdx.x >> 2);
    int s = threadIdx.x & 3;
    int qjj = q + (q >> 10);
    float qx = sxx[qjj], qy = sxy[qjj], qz = sxz[qjj];
    // sq = ((x*x + y*y) + z*z) sequential f32, no FMA — bit-exact vs numpy f32
    float qsq = __fadd_rn(__fadd_rn(__fmul_rn(qx, qx), __fmul_rn(qy, qy)), __fmul_rn(qz, qz));

    float bd0=3.0e38f,bd1=3.0e38f,bd2=3.0e38f,bd3=3.0e38f,bd4=3.0e38f,bd5=3.0e38f,bd6=3.0e38f,bd7=3.0e38f,
          bd8=3.0e38f,bd9=3.0e38f,bd10=3.0e38f,bd11=3.0e38f,bd12=3.0e38f,bd13=3.0e38f,bd14=3.0e38f,bd15=3.0e38f;
    int bi0=0,bi1=0,bi2=0,bi3=0,bi4=0,bi5=0,bi6=0,bi7=0,
        bi8=0,bi9=0,bi10=0,bi11=0,bi12=0,bi13=0,bi14=0,bi15=0;

#define INS1(t) { bool sm = cur_d < bd##t; float td = bd##t; int ti = bi##t; \
                  bd##t = sm ? cur_d : td; bi##t = sm ? cur_i : ti;          \
                  cur_d = sm ? td : cur_d; cur_i = sm ? ti : cur_i; }

    int j0 = s << 10;
    int jj0 = s * 1025;          // j + (j>>10) for this s-slice
    for (int m = 0; m < 1024; ++m) {
        float xj = sxx[jj0 + m], yj = sxy[jj0 + m], zj = sxz[jj0 + m];
        float sqj = __fadd_rn(__fadd_rn(__fmul_rn(xj, xj), __fmul_rn(yj, yj)), __fmul_rn(zj, zj));
        float dot = __fadd_rn(__fadd_rn(__fmul_rn(qx, xj), __fmul_rn(qy, yj)), __fmul_rn(qz, zj));
        // d2 = (sq_q + sq_j) - 2*dot, matching np broadcast-add then subtract
        float d = __fsub_rn(__fadd_rn(qsq, sqj), __fmul_rn(2.0f, dot));
        if (d < bd15) {   // strict <: equal-d later-index loses, matching top_k
            float cur_d = d; int cur_i = j0 + m;
            INS1(0) INS1(1) INS1(2) INS1(3) INS1(4) INS1(5) INS1(6) INS1(7)
            INS1(8) INS1(9) INS1(10) INS1(11) INS1(12) INS1(13) INS1(14) INS1(15)
        }
    }
#undef INS1

    {
        int base = threadIdx.x * 16;   // tid = q_local*4 + s
        md[base+0]=bd0;  mi[base+0]=(unsigned short)bi0;
        md[base+1]=bd1;  mi[base+1]=(unsigned short)bi1;
        md[base+2]=bd2;  mi[base+2]=(unsigned short)bi2;
        md[base+3]=bd3;  mi[base+3]=(unsigned short)bi3;
        md[base+4]=bd4;  mi[base+4]=(unsigned short)bi4;
        md[base+5]=bd5;  mi[base+5]=(unsigned short)bi5;
        md[base+6]=bd6;  mi[base+6]=(unsigned short)bi6;
        md[base+7]=bd7;  mi[base+7]=(unsigned short)bi7;
        md[base+8]=bd8;  mi[base+8]=(unsigned short)bi8;
        md[base+9]=bd9;  mi[base+9]=(unsigned short)bi9;
        md[base+10]=bd10; mi[base+10]=(unsigned short)bi10;
        md[base+11]=bd11; mi[base+11]=(unsigned short)bi11;
        md[base+12]=bd12; mi[base+12]=(unsigned short)bi12;
        md[base+13]=bd13; mi[base+13]=(unsigned short)bi13;
        md[base+14]=bd14; mi[base+14]=(unsigned short)bi14;
        md[base+15]=bd15; mi[base+15]=(unsigned short)bi15;
    }
    __syncthreads();
    if (s == 0) {
        int r = threadIdx.x * 16;    // rows r, r+16, r+32, r+48 hold the 4 partial lists
        int p0=0,p1=0,p2=0,p3=0;
        int out_base = (b*NPTS + q) * KNN;
        #pragma unroll
        for (int t = 0; t < 16; ++t) {
            float d0 = md[r+p0];    int i0 = mi[r+p0];
            float d1 = md[r+16+p1]; int i1 = mi[r+16+p1];
            float d2 = md[r+32+p2]; int i2 = mi[r+32+p2];
            float d3 = md[r+48+p3]; int i3 = mi[r+48+p3];
            float bdv = d0; int bii = i0; int which = 0;
            if (d1 < bdv || (d1 == bdv && i1 < bii)) { bdv=d1; bii=i1; which=1; }
            if (d2 < bdv || (d2 == bdv && i2 < bii)) { bdv=d2; bii=i2; which=2; }
            if (d3 < bdv || (d3 == bdv && i3 < bii)) { bdv=d3; bii=i3; which=3; }
            knn_idx[out_base + t] = bii;
            if (which==0) p0++; else if (which==1) p1++; else if (which==2) p2++; else p3++;
        }
    }
}

// ---------------- pack w_d2 / w_g1 / w_g2 into MFMA B-fragment layout (bf16) ----------------
// layout: [g][kt][nt][lane][i]  value = w[kt*32 + (lane>>4)*8 + i][nt*16 + (lane&15)]
__global__ __launch_bounds__(256) void pack_kernel(const float* __restrict__ w_d2,
                                                   const float* __restrict__ w_g1,
                                                   const float* __restrict__ w_g2,
                                                   unsigned short* __restrict__ wpack) {
    int t = blockIdx.x * 256 + threadIdx.x;
    if (t >= 3*4*8*64) return;
    int lane = t & 63;
    int nt = (t >> 6) & 7;
    int kt = (t >> 9) & 3;
    int g  = t >> 11;
    const float* w = (g == 0) ? w_d2 : (g == 1) ? w_g1 : w_g2;
    int colbase = nt*16 + (lane & 15);
    int kbase   = kt*32 + (lane >> 4)*8;
    union { unsigned short us[8]; uintx4 v; } u;
    #pragma unroll
    for (int i = 0; i < 8; ++i) u.us[i] = f2bf(w[(kbase+i)*DM + colbase]);
    ((uintx4*)wpack)[t] = u.v;
}

// ---------------- fc1 + q/k/v projection (f32 compute, bf16 outputs) ----------------
__global__ __launch_bounds__(256) void qkv_kernel(
    const float* __restrict__ features, const float* __restrict__ w_fc1, const float* __restrict__ b_fc1,
    const float* __restrict__ w_q, const float* __restrict__ w_k, const float* __restrict__ w_v,
    unsigned short* __restrict__ qo, unsigned short* __restrict__ ko, unsigned short* __restrict__ vo) {
    extern __shared__ char smem[];
    float* sfeat = (float*)smem;                       // [64][64]  16 KB
    float* sxbuf = (float*)(smem + 16384);             // [64][128] 32 KB
    float* swt   = (float*)(smem + 16384 + 32768);     // [128][128] 64 KB
    int rowbase = blockIdx.x * 64;

    for (int t = threadIdx.x; t < 64*64/4; t += 256)
        ((float4*)sfeat)[t] = ((const float4*)(features + rowbase*DPTS))[t];
    for (int t = threadIdx.x; t < 64*DM/4; t += 256)
        ((float4*)swt)[t] = ((const float4*)w_fc1)[t];
    __syncthreads();

    int r  = threadIdx.x >> 2;
    int cg = (threadIdx.x & 3) * 32;
    {
        float acc[32];
        #pragma unroll
        for (int cc = 0; cc < 32; ++cc) acc[cc] = b_fc1[cg + cc];
        for (int h = 0; h < 64; ++h) {
            float f = sfeat[r*64 + h];
            #pragma unroll
            for (int cc = 0; cc < 32; ++cc) acc[cc] += f * swt[h*DM + cg + cc];
        }
        #pragma unroll
        for (int cc = 0; cc < 32; ++cc) sxbuf[r*DM + cg + cc] = acc[cc];
    }
    __syncthreads();

    for (int g = 0; g < 3; ++g) {
        const float* wsrc = (g == 0) ? w_q : (g == 1) ? w_k : w_v;
        unsigned short* op = ((g == 0) ? qo : (g == 1) ? ko : vo) + (rowbase + r)*DM + cg;
        for (int t = threadIdx.x; t < DM*DM/4; t += 256)
            ((float4*)swt)[t] = ((const float4*)wsrc)[t];
        __syncthreads();
        float a2[32];
        #pragma unroll
        for (int cc = 0; cc < 32; ++cc) a2[cc] = 0.f;
        for (int h = 0; h < DM; ++h) {
            float xv = sxbuf[r*DM + h];
            #pragma unroll
            for (int cc = 0; cc < 32; ++cc) a2[cc] += xv * swt[h*DM + cg + cc];
        }
        #pragma unroll
        for (int cc = 0; cc < 32; ++cc) op[cc] = f2bf(a2[cc]);
        __syncthreads();
    }
}

// ---------------- main fused per-point kernel ----------------
// one wave per point (4 pts/wave sequentially), 4 waves/block
// LDS: wpack 96 KB | w_d1 1.5 KB | biases 2 KB | per-wave {pe,a1,v bf16[16][128], rel, idx, res}
__global__ __launch_bounds__(256) void main_kernel(
    const float* __restrict__ xyz, const float* __restrict__ features,
    const float* __restrict__ w_fc2, const float* __restrict__ b_fc2,
    const float* __restrict__ w_d1, const float* __restrict__ b_d1,
    const float* __restrict__ b_d2, const float* __restrict__ b_g1, const float* __restrict__ b_g2,
    const unsigned short* __restrict__ qg, const unsigned short* __restrict__ kg,
    const unsigned short* __restrict__ vg,
    const int* __restrict__ knn_idx, const unsigned short* __restrict__ wpack,
    float* __restrict__ res_out, float* __restrict__ attn_out) {
    extern __shared__ char smem[];
    unsigned short* swp = (unsigned short*)smem;          // 98304 B
    float* sw_d1 = (float*)(smem + 98304);                // 1536 B
    float* sb_d1 = (float*)(smem + 99840);
    float* sb_d2 = (float*)(smem + 100352);
    float* sb_g1 = (float*)(smem + 100864);
    float* sb_g2 = (float*)(smem + 101376);

    for (int t = threadIdx.x; t < 98304/16; t += 256)
        ((uintx4*)swp)[t] = ((const uintx4*)wpack)[t];
    for (int t = threadIdx.x; t < 384; t += 256) sw_d1[t] = w_d1[t];
    if (threadIdx.x < 128) {
        sb_d1[threadIdx.x] = b_d1[threadIdx.x];
        sb_d2[threadIdx.x] = b_d2[threadIdx.x];
        sb_g1[threadIdx.x] = b_g1[threadIdx.x];
        sb_g2[threadIdx.x] = b_g2[threadIdx.x];
    }
    __syncthreads();

    int wave = threadIdx.x >> 6;
    int lane = threadIdx.x & 63;
    int nbr  = lane & 15;     // A-operand M index / D-output column-in-tile
    int cblk = lane >> 4;
    char* wbase = smem + 101888 + wave * 13056;
    unsigned short* pe_l = (unsigned short*)wbase;          // [16][128] bf16 swizzled
    unsigned short* a1_l = (unsigned short*)(wbase + 4096);
    unsigned short* v_l  = (unsigned short*)(wbase + 8192);
    float* rel_l = (float*)(wbase + 12288);                 // [16][3]
    int*   idx_l = (int*)(wbase + 12480);                   // [16]
    float* res_l = (float*)(wbase + 12544);                 // [128]

    const float inv_sqrt_d = 0.08838834764831845f;          // 1/sqrt(128)

    for (int pt = 0; pt < 4; ++pt) {
        int p = (blockIdx.x * 4 + wave) * 4 + pt;
        int b = p >> 12, n = p & 4095;
        int pbase = b * NPTS + n;

        // phase 0: neighbor idx + rel
        if (lane < 16) {
            int id = knn_idx[pbase*KNN + lane];
            idx_l[lane] = id;
            const float* cp = xyz + (b*NPTS + id)*3;
            const float* qp = xyz + pbase*3;
            rel_l[lane*3+0] = qp[0] - cp[0];
            rel_l[lane*3+1] = qp[1] - cp[1];
            rel_l[lane*3+2] = qp[2] - cp[2];
        }
        __syncthreads();

        int myidx = idx_l[nbr];
        // phase 1a: gather V rows -> v_l (swizzled)
        {
            const unsigned short* vp = vg + (b*NPTS + myidx)*DM;
            #pragma unroll
            for (int kt = 0; kt < 4; ++kt) {
                int c8 = kt*32 + cblk*8;
                uintx4 vr = *((const uintx4*)(vp + c8));
                int byte = (nbr*256 + c8*2) ^ ((nbr & 7) << 4);
                *(uintx4*)(( char*)v_l + byte) = vr;
            }
        }
        // phase 1b: h1 = relu(rel @ w_d1 + b_d1), A-frag layout
        short8 af[4];
        {
            float r0 = rel_l[nbr*3+0], r1 = rel_l[nbr*3+1], r2 = rel_l[nbr*3+2];
            #pragma unroll
            for (int kt = 0; kt < 4; ++kt) {
                #pragma unroll
                for (int i = 0; i < 8; ++i) {
                    int c = kt*32 + cblk*8 + i;
                    float h = r0*sw_d1[c] + r1*sw_d1[DM + c] + r2*sw_d1[2*DM + c] + sb_d1[c];
                    h = fmaxf(h, 0.f);
                    af[kt][i] = (short)f2bf(h);
                }
            }
        }
        // phase 1c: pe = h1 @ w_d2 + b_d2  (GEMM 0)
        for (int nt = 0; nt < 8; ++nt) {
            floatx4 acc = {0.f, 0.f, 0.f, 0.f};
            #pragma unroll
            for (int kt = 0; kt < 4; ++kt) {
                short8 bf = *((const short8*)(swp + ((0*4 + kt)*8 + nt)*512 + lane*8));
                acc = __builtin_amdgcn_mfma_f32_16x16x32_bf16(af[kt], bf, acc, 0, 0, 0);
            }
            int c = nt*16 + nbr;
            #pragma unroll
            for (int rg = 0; rg < 4; ++rg) {
                int krow = cblk*4 + rg;
                float pv = acc[rg] + sb_d2[c];
                int byte = (krow*256 + c*2) ^ ((krow & 7) << 4);
                *(unsigned short*)((char*)pe_l + byte) = f2bf(pv);
            }
        }
        __syncthreads();

        // phase 2: t = q - k_g + pe -> A-frags ; a1 = relu(t @ w_g1 + b_g1) (GEMM 1)
        short8 tf[4];
        {
            const unsigned short* kp = kg + (b*NPTS + myidx)*DM;
            const unsigned short* qp = qg + pbase*DM;
            #pragma unroll
            for (int kt = 0; kt < 4; ++kt) {
                int c8 = kt*32 + cblk*8;
                uintx4 kr = *((const uintx4*)(kp + c8));
                uintx4 qr = *((const uintx4*)(qp + c8));
                int byte = (nbr*256 + c8*2) ^ ((nbr & 7) << 4);
                uintx4 pr = *(const uintx4*)((char*)pe_l + byte);
                #pragma unroll
                for (int w2 = 0; w2 < 4; ++w2) {
                    float k0 = bf2f((unsigned short)(kr[w2] & 0xffffu));
                    float k1 = bf2f((unsigned short)(kr[w2] >> 16));
                    float q0 = bf2f((unsigned short)(qr[w2] & 0xffffu));
                    float q1 = bf2f((unsigned short)(qr[w2] >> 16));
                    float p0 = bf2f((unsigned short)(pr[w2] & 0xffffu));
                    float p1 = bf2f((unsigned short)(pr[w2] >> 16));
                    tf[kt][w2*2]   = (short)f2bf(q0 - k0 + p0);
                    tf[kt][w2*2+1] = (short)f2bf(q1 - k1 + p1);
                }
            }
        }
        for (int nt = 0; nt < 8; ++nt) {
            floatx4 acc = {0.f, 0.f, 0.f, 0.f};
            #pragma unroll
            for (int kt = 0; kt < 4; ++kt) {
                short8 bf = *((const short8*)(swp + ((1*4 + kt)*8 + nt)*512 + lane*8));
                acc = __builtin_amdgcn_mfma_f32_16x16x32_bf16(tf[kt], bf, acc, 0, 0, 0);
            }
            int c = nt*16 + nbr;
            #pragma unroll
            for (int rg = 0; rg < 4; ++rg) {
                int krow = cblk*4 + rg;
                float av = fmaxf(acc[rg] + sb_g1[c], 0.f);
                int byte = (krow*256 + c*2) ^ ((krow & 7) << 4);
                *(unsigned short*)((char*)a1_l + byte) = f2bf(av);
            }
        }
        __syncthreads();

        // phase 3: s = (a1 @ w_g2 + b_g2)/sqrt(D); softmax over K; attn out; res partial
        short8 a1f[4];
        #pragma unroll
        for (int kt = 0; kt < 4; ++kt) {
            int c8 = kt*32 + cblk*8;
            int byte = (nbr*256 + c8*2) ^ ((nbr & 7) << 4);
            a1f[kt] = *(const short8*)((char*)a1_l + byte);
        }
        for (int nt = 0; nt < 8; ++nt) {
            floatx4 acc = {0.f, 0.f, 0.f, 0.f};
            #pragma unroll
            for (int kt = 0; kt < 4; ++kt) {
                short8 bf = *((const short8*)(swp + ((2*4 + kt)*8 + nt)*512 + lane*8));
                acc = __builtin_amdgcn_mfma_f32_16x16x32_bf16(a1f[kt], bf, acc, 0, 0, 0);
            }
            int c = nt*16 + nbr;
            float s[4];
            #pragma unroll
            for (int rg = 0; rg < 4; ++rg) s[rg] = (acc[rg] + sb_g2[c]) * inv_sqrt_d;
            float mx = fmaxf(fmaxf(s[0], s[1]), fmaxf(s[2], s[3]));
            mx = fmaxf(mx, __shfl_xor(mx, 16));
            mx = fmaxf(mx, __shfl_xor(mx, 32));
            float e[4]; float sum = 0.f;
            #pragma unroll
            for (int rg = 0; rg < 4; ++rg) { e[rg] = __expf(s[rg] - mx); sum += e[rg]; }
            sum += __shfl_xor(sum, 16);
            sum += __shfl_xor(sum, 32);
            float inv = 1.f / sum;
            float rpart = 0.f;
            #pragma unroll
            for (int rg = 0; rg < 4; ++rg) {
                float a = e[rg] * inv;
                int krow = cblk*4 + rg;
                attn_out[(pbase*KNN + krow)*DM + c] = a;
                int byte = (krow*256 + c*2) ^ ((krow & 7) << 4);
                float vv = bf2f(*(const unsigned short*)((char*)v_l + byte));
                float pv = bf2f(*(const unsigned short*)((char*)pe_l + byte));
                rpart += a * (vv + pv);
            }
            rpart += __shfl_xor(rpart, 16);
            rpart += __shfl_xor(rpart, 32);
            if (lane < 16) res_l[nt*16 + lane] = rpart;
        }
        __syncthreads();

        // phase 4: res = res_l @ w_fc2 + b_fc2 + features
        {
            float accr = 0.f;
            #pragma unroll 4
            for (int c = 0; c < DM; ++c) accr += res_l[c] * w_fc2[c*DPTS + lane];
            res_out[pbase*DPTS + lane] = accr + b_fc2[lane] + features[pbase*DPTS + lane];
        }
        __syncthreads();
    }
}

extern "C" void kernel_launch(void* const* d_in, const int* in_sizes, int n_in,
                              void* d_out, int out_size, void* d_ws, size_t ws_size,
                              hipStream_t stream) {
    const float* xyz      = (const float*)d_in[0];
    const float* features = (const float*)d_in[1];
    const float* w_fc1    = (const float*)d_in[2];
    const float* b_fc1    = (const float*)d_in[3];
    const float* w_fc2    = (const float*)d_in[4];
    const float* b_fc2    = (const float*)d_in[5];
    const float* w_d1     = (const float*)d_in[6];
    const float* b_d1     = (const float*)d_in[7];
    const float* w_d2     = (const float*)d_in[8];
    const float* b_d2     = (const float*)d_in[9];
    const float* w_g1     = (const float*)d_in[10];
    const float* b_g1     = (const float*)d_in[11];
    const float* w_g2     = (const float*)d_in[12];
    const float* b_g2     = (const float*)d_in[13];
    const float* w_q      = (const float*)d_in[14];
    const float* w_k      = (const float*)d_in[15];
    const float* w_v      = (const float*)d_in[16];

    char* ws = (char*)d_ws;
    int* knn            = (int*)ws;                                  // 1 MB
    unsigned short* qb  = (unsigned short*)(ws + (1 << 20));         // 4 MB
    unsigned short* kb  = (unsigned short*)(ws + (5 << 20));         // 4 MB
    unsigned short* vb  = (unsigned short*)(ws + (9 << 20));         // 4 MB
    unsigned short* wpk = (unsigned short*)(ws + (13 << 20));        // 96 KB

    float* res_out  = (float*)d_out;
    float* attn_out = res_out + BATCH*NPTS*DPTS;

    pack_kernel<<<dim3(24), dim3(256), 0, stream>>>(w_d2, w_g1, w_g2, wpk);
    knn_kernel<<<dim3(256), dim3(256), 73776, stream>>>(xyz, knn);
    qkv_kernel<<<dim3(256), dim3(256), 114688, stream>>>(features, w_fc1, b_fc1,
                                                         w_q, w_k, w_v, qb, kb, vb);
    main_kernel<<<dim3(1024), dim3(256), 154112, stream>>>(
        xyz, features, w_fc2, b_fc2, w_d1, b_d1, b_d2, b_g1, b_g2,
        qb, kb, vb, knn, wpk, res_out, attn_out);
}

// Round 10
// 858.132 us; speedup vs baseline: 1.6336x; 1.0534x over previous
//
#include <hip/hip_runtime.h>
#include <math.h>

#define BATCH 4
#define NPTS 4096
#define KNN 16
#define DPTS 64
#define DM 128

typedef __attribute__((ext_vector_type(8))) short short8;
typedef __attribute__((ext_vector_type(4))) float floatx4;
typedef __attribute__((ext_vector_type(4))) unsigned int uintx4;

// wave-local LDS fence: per-wave buffers need no block barrier (rule #18: sched_barrier after asm waitcnt)
#define WFENCE() do { asm volatile("s_waitcnt lgkmcnt(0)" ::: "memory"); \
                      __builtin_amdgcn_sched_barrier(0); } while (0)

static __device__ __forceinline__ float bf2f(unsigned short h) {
    union { unsigned int u; float f; } c; c.u = ((unsigned int)h) << 16; return c.f;
}
static __device__ __forceinline__ unsigned short f2bf(float f) {
    union { float f; unsigned int u; } c; c.f = f;
    unsigned int u = c.u;
    u += 0x7fffu + ((u >> 16) & 1u);   // RNE
    return (unsigned short)(u >> 16);
}

// ---------------- kNN v3: bit-exact f32 expanded-form distances, register-resident top-16 ----
// v2 (r7): 268us, VALUBusy 57%, Occ 11.5% — grid 256 = 1 block/CU, serial INS chain latency exposed.
// v3: 8 slices x 512 cand x 32 queries/block -> grid 512 = 2 blocks/CU (2 waves/SIMD hide the chain);
//     merge arrays aliased onto dead coords region; ssq kept; LDS 65.7KB.
__global__ __launch_bounds__(256) void knn_kernel(const float* __restrict__ xyz,
                                                  int* __restrict__ knn_idx) {
    extern __shared__ char smem[];
    float* sxx = (float*)smem;                    // 4104 f32 each (+1 pad per 512)
    float* sxy = sxx + 4104;
    float* sxz = sxy + 4104;
    float* ssq = sxz + 4104;
    // aliased over coords after the scan (coords dead):
    float* md          = (float*)smem;                     // [256][16] f32
    unsigned short* mi = (unsigned short*)(smem + 16384);  // [256][16] u16

    int b = blockIdx.x >> 7;               // 128 blocks per batch
    int qbase = (blockIdx.x & 127) * 32;   // 32 queries per block
    const float* bx = xyz + b * NPTS * 3;
    for (int j = threadIdx.x; j < NPTS; j += 256) {
        int jj = j + (j >> 9);
        float x = bx[j*3+0], y = bx[j*3+1], z = bx[j*3+2];
        sxx[jj] = x; sxy[jj] = y; sxz[jj] = z;
        // sq = ((x*x + y*y) + z*z) sequential f32, no FMA — bit-exact vs numpy f32
        ssq[jj] = __fadd_rn(__fadd_rn(__fmul_rn(x, x), __fmul_rn(y, y)), __fmul_rn(z, z));
    }
    __syncthreads();

    int q = qbase + (threadIdx.x >> 3);
    int s = threadIdx.x & 7;
    int qjj = q + (q >> 9);
    float qx = sxx[qjj], qy = sxy[qjj], qz = sxz[qjj];
    float qsq = ssq[qjj];

    float bd0=3.0e38f,bd1=3.0e38f,bd2=3.0e38f,bd3=3.0e38f,bd4=3.0e38f,bd5=3.0e38f,bd6=3.0e38f,bd7=3.0e38f,
          bd8=3.0e38f,bd9=3.0e38f,bd10=3.0e38f,bd11=3.0e38f,bd12=3.0e38f,bd13=3.0e38f,bd14=3.0e38f,bd15=3.0e38f;
    int bi0=0,bi1=0,bi2=0,bi3=0,bi4=0,bi5=0,bi6=0,bi7=0,
        bi8=0,bi9=0,bi10=0,bi11=0,bi12=0,bi13=0,bi14=0,bi15=0;

#define INS1(t) { bool sm = cur_d < bd##t; float td = bd##t; int ti = bi##t; \
                  bd##t = sm ? cur_d : td; bi##t = sm ? cur_i : ti;          \
                  cur_d = sm ? td : cur_d; cur_i = sm ? ti : cur_i; }

    int j0 = s << 9;
    int jj0 = 513 * s;           // j + (j>>9) at slice base
    for (int m = 0; m < 512; ++m) {
        float xj = sxx[jj0 + m], yj = sxy[jj0 + m], zj = sxz[jj0 + m];
        float sqj = ssq[jj0 + m];
        // dot = ((xq*xj + yq*yj) + zq*zj) sequential f32, no FMA
        float dot = __fadd_rn(__fadd_rn(__fmul_rn(qx, xj), __fmul_rn(qy, yj)), __fmul_rn(qz, zj));
        // d2 = (sq_q + sq_j) - 2*dot, matching np broadcast-add then subtract
        float d = __fsub_rn(__fadd_rn(qsq, sqj), __fmul_rn(2.0f, dot));
        if (d < bd15) {   // strict <: equal-d later-index loses, matching top_k
            float cur_d = d; int cur_i = j0 + m;
            INS1(0) INS1(1) INS1(2) INS1(3) INS1(4) INS1(5) INS1(6) INS1(7)
            INS1(8) INS1(9) INS1(10) INS1(11) INS1(12) INS1(13) INS1(14) INS1(15)
        }
    }
#undef INS1

    __syncthreads();   // all coord/ssq reads complete before aliasing writes
    {
        int base = threadIdx.x * 16;   // tid = q_local*8 + s
        md[base+0]=bd0;  mi[base+0]=(unsigned short)bi0;
        md[base+1]=bd1;  mi[base+1]=(unsigned short)bi1;
        md[base+2]=bd2;  mi[base+2]=(unsigned short)bi2;
        md[base+3]=bd3;  mi[base+3]=(unsigned short)bi3;
        md[base+4]=bd4;  mi[base+4]=(unsigned short)bi4;
        md[base+5]=bd5;  mi[base+5]=(unsigned short)bi5;
        md[base+6]=bd6;  mi[base+6]=(unsigned short)bi6;
        md[base+7]=bd7;  mi[base+7]=(unsigned short)bi7;
        md[base+8]=bd8;  mi[base+8]=(unsigned short)bi8;
        md[base+9]=bd9;  mi[base+9]=(unsigned short)bi9;
        md[base+10]=bd10; mi[base+10]=(unsigned short)bi10;
        md[base+11]=bd11; mi[base+11]=(unsigned short)bi11;
        md[base+12]=bd12; mi[base+12]=(unsigned short)bi12;
        md[base+13]=bd13; mi[base+13]=(unsigned short)bi13;
        md[base+14]=bd14; mi[base+14]=(unsigned short)bi14;
        md[base+15]=bd15; mi[base+15]=(unsigned short)bi15;
    }
    __syncthreads();
    if (s == 0) {
        int r = threadIdx.x * 16;   // rows r, r+16, ..., r+112 hold the 8 partial lists
        int p0=0,p1=0,p2=0,p3=0,p4=0,p5=0,p6=0,p7=0;
        int out_base = (b*NPTS + q) * KNN;
        #pragma unroll
        for (int t = 0; t < 16; ++t) {
            float bdv = md[r+p0];      int bii = mi[r+p0];      int which = 0;
            { float dd = md[r+16+p1];  int ii = mi[r+16+p1];  if (dd < bdv || (dd == bdv && ii < bii)) { bdv=dd; bii=ii; which=1; } }
            { float dd = md[r+32+p2];  int ii = mi[r+32+p2];  if (dd < bdv || (dd == bdv && ii < bii)) { bdv=dd; bii=ii; which=2; } }
            { float dd = md[r+48+p3];  int ii = mi[r+48+p3];  if (dd < bdv || (dd == bdv && ii < bii)) { bdv=dd; bii=ii; which=3; } }
            { float dd = md[r+64+p4];  int ii = mi[r+64+p4];  if (dd < bdv || (dd == bdv && ii < bii)) { bdv=dd; bii=ii; which=4; } }
            { float dd = md[r+80+p5];  int ii = mi[r+80+p5];  if (dd < bdv || (dd == bdv && ii < bii)) { bdv=dd; bii=ii; which=5; } }
            { float dd = md[r+96+p6];  int ii = mi[r+96+p6];  if (dd < bdv || (dd == bdv && ii < bii)) { bdv=dd; bii=ii; which=6; } }
            { float dd = md[r+112+p7]; int ii = mi[r+112+p7]; if (dd < bdv || (dd == bdv && ii < bii)) { bdv=dd; bii=ii; which=7; } }
            knn_idx[out_base + t] = bii;
            if (which==0) p0++; else if (which==1) p1++; else if (which==2) p2++; else if (which==3) p3++;
            else if (which==4) p4++; else if (which==5) p5++; else if (which==6) p6++; else p7++;
        }
    }
}

// ---------------- pack w_d2 / w_g1 / w_g2 into MFMA B-fragment layout (bf16) ----------------
// layout: [g][kt][nt][lane][i]  value = w[kt*32 + (lane>>4)*8 + i][nt*16 + (lane&15)]
__global__ __launch_bounds__(256) void pack_kernel(const float* __restrict__ w_d2,
                                                   const float* __restrict__ w_g1,
                                                   const float* __restrict__ w_g2,
                                                   unsigned short* __restrict__ wpack) {
    int t = blockIdx.x * 256 + threadIdx.x;
    if (t >= 3*4*8*64) return;
    int lane = t & 63;
    int nt = (t >> 6) & 7;
    int kt = (t >> 9) & 3;
    int g  = t >> 11;
    const float* w = (g == 0) ? w_d2 : (g == 1) ? w_g1 : w_g2;
    int colbase = nt*16 + (lane & 15);
    int kbase   = kt*32 + (lane >> 4)*8;
    union { unsigned short us[8]; uintx4 v; } u;
    #pragma unroll
    for (int i = 0; i < 8; ++i) u.us[i] = f2bf(w[(kbase+i)*DM + colbase]);
    ((uintx4*)wpack)[t] = u.v;
}

// ---------------- fc1 + q/k/v projection (f32 compute, bf16 outputs) ----------------
__global__ __launch_bounds__(256) void qkv_kernel(
    const float* __restrict__ features, const float* __restrict__ w_fc1, const float* __restrict__ b_fc1,
    const float* __restrict__ w_q, const float* __restrict__ w_k, const float* __restrict__ w_v,
    unsigned short* __restrict__ qo, unsigned short* __restrict__ ko, unsigned short* __restrict__ vo) {
    extern __shared__ char smem[];
    float* sfeat = (float*)smem;                       // [64][64]  16 KB
    float* sxbuf = (float*)(smem + 16384);             // [64][128] 32 KB
    float* swt   = (float*)(smem + 16384 + 32768);     // [128][128] 64 KB
    int rowbase = blockIdx.x * 64;

    for (int t = threadIdx.x; t < 64*64/4; t += 256)
        ((float4*)sfeat)[t] = ((const float4*)(features + rowbase*DPTS))[t];
    for (int t = threadIdx.x; t < 64*DM/4; t += 256)
        ((float4*)swt)[t] = ((const float4*)w_fc1)[t];
    __syncthreads();

    int r  = threadIdx.x >> 2;
    int cg = (threadIdx.x & 3) * 32;
    {
        float acc[32];
        #pragma unroll
        for (int cc = 0; cc < 32; ++cc) acc[cc] = b_fc1[cg + cc];
        for (int h = 0; h < 64; ++h) {
            float f = sfeat[r*64 + h];
            #pragma unroll
            for (int cc = 0; cc < 32; ++cc) acc[cc] += f * swt[h*DM + cg + cc];
        }
        #pragma unroll
        for (int cc = 0; cc < 32; ++cc) sxbuf[r*DM + cg + cc] = acc[cc];
    }
    __syncthreads();

    for (int g = 0; g < 3; ++g) {
        const float* wsrc = (g == 0) ? w_q : (g == 1) ? w_k : w_v;
        unsigned short* op = ((g == 0) ? qo : (g == 1) ? ko : vo) + (rowbase + r)*DM + cg;
        for (int t = threadIdx.x; t < DM*DM/4; t += 256)
            ((float4*)swt)[t] = ((const float4*)wsrc)[t];
        __syncthreads();
        float a2[32];
        #pragma unroll
        for (int cc = 0; cc < 32; ++cc) a2[cc] = 0.f;
        for (int h = 0; h < DM; ++h) {
            float xv = sxbuf[r*DM + h];
            #pragma unroll
            for (int cc = 0; cc < 32; ++cc) a2[cc] += xv * swt[h*DM + cg + cc];
        }
        #pragma unroll
        for (int cc = 0; cc < 32; ++cc) op[cc] = f2bf(a2[cc]);
        __syncthreads();
    }
}

// ---------------- main fused per-point kernel ----------------
// one wave per point (4 pts/wave sequentially), 4 waves/block
// r8 change: all in-loop __syncthreads -> WFENCE (per-wave buffers only; swp read-only after init)
// so the 4 waves drift and overlap gather latency against MFMA.
__global__ __launch_bounds__(256) void main_kernel(
    const float* __restrict__ xyz, const float* __restrict__ features,
    const float* __restrict__ w_fc2, const float* __restrict__ b_fc2,
    const float* __restrict__ w_d1, const float* __restrict__ b_d1,
    const float* __restrict__ b_d2, const float* __restrict__ b_g1, const float* __restrict__ b_g2,
    const unsigned short* __restrict__ qg, const unsigned short* __restrict__ kg,
    const unsigned short* __restrict__ vg,
    const int* __restrict__ knn_idx, const unsigned short* __restrict__ wpack,
    float* __restrict__ res_out, float* __restrict__ attn_out) {
    extern __shared__ char smem[];
    unsigned short* swp = (unsigned short*)smem;          // 98304 B
    float* sw_d1 = (float*)(smem + 98304);                // 1536 B
    float* sb_d1 = (float*)(smem + 99840);
    float* sb_d2 = (float*)(smem + 100352);
    float* sb_g1 = (float*)(smem + 100864);
    float* sb_g2 = (float*)(smem + 101376);

    for (int t = threadIdx.x; t < 98304/16; t += 256)
        ((uintx4*)swp)[t] = ((const uintx4*)wpack)[t];
    for (int t = threadIdx.x; t < 384; t += 256) sw_d1[t] = w_d1[t];
    if (threadIdx.x < 128) {
        sb_d1[threadIdx.x] = b_d1[threadIdx.x];
        sb_d2[threadIdx.x] = b_d2[threadIdx.x];
        sb_g1[threadIdx.x] = b_g1[threadIdx.x];
        sb_g2[threadIdx.x] = b_g2[threadIdx.x];
    }
    __syncthreads();   // swp/biases shared across waves: keep this one

    int wave = threadIdx.x >> 6;
    int lane = threadIdx.x & 63;
    int nbr  = lane & 15;     // A-operand M index / D-output column-in-tile
    int cblk = lane >> 4;
    char* wbase = smem + 101888 + wave * 13056;
    unsigned short* pe_l = (unsigned short*)wbase;          // [16][128] bf16 swizzled
    unsigned short* a1_l = (unsigned short*)(wbase + 4096);
    unsigned short* v_l  = (unsigned short*)(wbase + 8192);
    float* rel_l = (float*)(wbase + 12288);                 // [16][3]
    int*   idx_l = (int*)(wbase + 12480);                   // [16]
    float* res_l = (float*)(wbase + 12544);                 // [128]

    const float inv_sqrt_d = 0.08838834764831845f;          // 1/sqrt(128)

    for (int pt = 0; pt < 4; ++pt) {
        int p = (blockIdx.x * 4 + wave) * 4 + pt;
        int b = p >> 12, n = p & 4095;
        int pbase = b * NPTS + n;

        // phase 0: neighbor idx + rel
        if (lane < 16) {
            int id = knn_idx[pbase*KNN + lane];
            idx_l[lane] = id;
            const float* cp = xyz + (b*NPTS + id)*3;
            const float* qp = xyz + pbase*3;
            rel_l[lane*3+0] = qp[0] - cp[0];
            rel_l[lane*3+1] = qp[1] - cp[1];
            rel_l[lane*3+2] = qp[2] - cp[2];
        }
        WFENCE();

        int myidx = idx_l[nbr];
        // phase 1a: gather V rows -> v_l (swizzled)
        {
            const unsigned short* vp = vg + (b*NPTS + myidx)*DM;
            #pragma unroll
            for (int kt = 0; kt < 4; ++kt) {
                int c8 = kt*32 + cblk*8;
                uintx4 vr = *((const uintx4*)(vp + c8));
                int byte = (nbr*256 + c8*2) ^ ((nbr & 7) << 4);
                *(uintx4*)(( char*)v_l + byte) = vr;
            }
        }
        // phase 1b: h1 = relu(rel @ w_d1 + b_d1), A-frag layout
        short8 af[4];
        {
            float r0 = rel_l[nbr*3+0], r1 = rel_l[nbr*3+1], r2 = rel_l[nbr*3+2];
            #pragma unroll
            for (int kt = 0; kt < 4; ++kt) {
                #pragma unroll
                for (int i = 0; i < 8; ++i) {
                    int c = kt*32 + cblk*8 + i;
                    float h = r0*sw_d1[c] + r1*sw_d1[DM + c] + r2*sw_d1[2*DM + c] + sb_d1[c];
                    h = fmaxf(h, 0.f);
                    af[kt][i] = (short)f2bf(h);
                }
            }
        }
        // phase 1c: pe = h1 @ w_d2 + b_d2  (GEMM 0)
        for (int nt = 0; nt < 8; ++nt) {
            floatx4 acc = {0.f, 0.f, 0.f, 0.f};
            #pragma unroll
            for (int kt = 0; kt < 4; ++kt) {
                short8 bf = *((const short8*)(swp + ((0*4 + kt)*8 + nt)*512 + lane*8));
                acc = __builtin_amdgcn_mfma_f32_16x16x32_bf16(af[kt], bf, acc, 0, 0, 0);
            }
            int c = nt*16 + nbr;
            #pragma unroll
            for (int rg = 0; rg < 4; ++rg) {
                int krow = cblk*4 + rg;
                float pv = acc[rg] + sb_d2[c];
                int byte = (krow*256 + c*2) ^ ((krow & 7) << 4);
                *(unsigned short*)((char*)pe_l + byte) = f2bf(pv);
            }
        }
        WFENCE();

        // phase 2: t = q - k_g + pe -> A-frags ; a1 = relu(t @ w_g1 + b_g1) (GEMM 1)
        short8 tf[4];
        {
            const unsigned short* kp = kg + (b*NPTS + myidx)*DM;
            const unsigned short* qp = qg + pbase*DM;
            #pragma unroll
            for (int kt = 0; kt < 4; ++kt) {
                int c8 = kt*32 + cblk*8;
                uintx4 kr = *((const uintx4*)(kp + c8));
                uintx4 qr = *((const uintx4*)(qp + c8));
                int byte = (nbr*256 + c8*2) ^ ((nbr & 7) << 4);
                uintx4 pr = *(const uintx4*)((char*)pe_l + byte);
                #pragma unroll
                for (int w2 = 0; w2 < 4; ++w2) {
                    float k0 = bf2f((unsigned short)(kr[w2] & 0xffffu));
                    float k1 = bf2f((unsigned short)(kr[w2] >> 16));
                    float q0 = bf2f((unsigned short)(qr[w2] & 0xffffu));
                    float q1 = bf2f((unsigned short)(qr[w2] >> 16));
                    float p0 = bf2f((unsigned short)(pr[w2] & 0xffffu));
                    float p1 = bf2f((unsigned short)(pr[w2] >> 16));
                    tf[kt][w2*2]   = (short)f2bf(q0 - k0 + p0);
                    tf[kt][w2*2+1] = (short)f2bf(q1 - k1 + p1);
                }
            }
        }
        for (int nt = 0; nt < 8; ++nt) {
            floatx4 acc = {0.f, 0.f, 0.f, 0.f};
            #pragma unroll
            for (int kt = 0; kt < 4; ++kt) {
                short8 bf = *((const short8*)(swp + ((1*4 + kt)*8 + nt)*512 + lane*8));
                acc = __builtin_amdgcn_mfma_f32_16x16x32_bf16(tf[kt], bf, acc, 0, 0, 0);
            }
            int c = nt*16 + nbr;
            #pragma unroll
            for (int rg = 0; rg < 4; ++rg) {
                int krow = cblk*4 + rg;
                float av = fmaxf(acc[rg] + sb_g1[c], 0.f);
                int byte = (krow*256 + c*2) ^ ((krow & 7) << 4);
                *(unsigned short*)((char*)a1_l + byte) = f2bf(av);
            }
        }
        WFENCE();

        // phase 3: s = (a1 @ w_g2 + b_g2)/sqrt(D); softmax over K; attn out; res partial
        short8 a1f[4];
        #pragma unroll
        for (int kt = 0; kt < 4; ++kt) {
            int c8 = kt*32 + cblk*8;
            int byte = (nbr*256 + c8*2) ^ ((nbr & 7) << 4);
            a1f[kt] = *(const short8*)((char*)a1_l + byte);
        }
        for (int nt = 0; nt < 8; ++nt) {
            floatx4 acc = {0.f, 0.f, 0.f, 0.f};
            #pragma unroll
            for (int kt = 0; kt < 4; ++kt) {
                short8 bf = *((const short8*)(swp + ((2*4 + kt)*8 + nt)*512 + lane*8));
                acc = __builtin_amdgcn_mfma_f32_16x16x32_bf16(a1f[kt], bf, acc, 0, 0, 0);
            }
            int c = nt*16 + nbr;
            float s[4];
            #pragma unroll
            for (int rg = 0; rg < 4; ++rg) s[rg] = (acc[rg] + sb_g2[c]) * inv_sqrt_d;
            float mx = fmaxf(fmaxf(s[0], s[1]), fmaxf(s[2], s[3]));
            mx = fmaxf(mx, __shfl_xor(mx, 16));
            mx = fmaxf(mx, __shfl_xor(mx, 32));
            float e[4]; float sum = 0.f;
            #pragma unroll
            for (int rg = 0; rg < 4; ++rg) { e[rg] = __expf(s[rg] - mx); sum += e[rg]; }
            sum += __shfl_xor(sum, 16);
            sum += __shfl_xor(sum, 32);
            float inv = 1.f / sum;
            float rpart = 0.f;
            #pragma unroll
            for (int rg = 0; rg < 4; ++rg) {
                float a = e[rg] * inv;
                int krow = cblk*4 + rg;
                attn_out[(pbase*KNN + krow)*DM + c] = a;
                int byte = (krow*256 + c*2) ^ ((krow & 7) << 4);
                float vv = bf2f(*(const unsigned short*)((char*)v_l + byte));
                float pv = bf2f(*(const unsigned short*)((char*)pe_l + byte));
                rpart += a * (vv + pv);
            }
            rpart += __shfl_xor(rpart, 16);
            rpart += __shfl_xor(rpart, 32);
            if (lane < 16) res_l[nt*16 + lane] = rpart;
        }
        WFENCE();

        // phase 4: res = res_l @ w_fc2 + b_fc2 + features
        {
            float accr = 0.f;
            #pragma unroll 4
            for (int c = 0; c < DM; ++c) accr += res_l[c] * w_fc2[c*DPTS + lane];
            res_out[pbase*DPTS + lane] = accr + b_fc2[lane] + features[pbase*DPTS + lane];
        }
        WFENCE();
    }
}

extern "C" void kernel_launch(void* const* d_in, const int* in_sizes, int n_in,
                              void* d_out, int out_size, void* d_ws, size_t ws_size,
                              hipStream_t stream) {
    const float* xyz      = (const float*)d_in[0];
    const float* features = (const float*)d_in[1];
    const float* w_fc1    = (const float*)d_in[2];
    const float* b_fc1    = (const float*)d_in[3];
    const float* w_fc2    = (const float*)d_in[4];
    const float* b_fc2    = (const float*)d_in[5];
    const float* w_d1     = (const float*)d_in[6];
    const float* b_d1     = (const float*)d_in[7];
    const float* w_d2     = (const float*)d_in[8];
    const float* b_d2     = (const float*)d_in[9];
    const float* w_g1     = (const float*)d_in[10];
    const float* b_g1     = (const float*)d_in[11];
    const float* w_g2     = (const float*)d_in[12];
    const float* b_g2     = (const float*)d_in[13];
    const float* w_q      = (const float*)d_in[14];
    const float* w_k      = (const float*)d_in[15];
    const float* w_v      = (const float*)d_in[16];

    char* ws = (char*)d_ws;
    int* knn            = (int*)ws;                                  // 1 MB
    unsigned short* qb  = (unsigned short*)(ws + (1 << 20));         // 4 MB
    unsigned short* kb  = (unsigned short*)(ws + (5 << 20));         // 4 MB
    unsigned short* vb  = (unsigned short*)(ws + (9 << 20));         // 4 MB
    unsigned short* wpk = (unsigned short*)(ws + (13 << 20));        // 96 KB

    float* res_out  = (float*)d_out;
    float* attn_out = res_out + BATCH*NPTS*DPTS;

    pack_kernel<<<dim3(24), dim3(256), 0, stream>>>(w_d2, w_g1, w_g2, wpk);
    knn_kernel<<<dim3(512), dim3(256), 65664, stream>>>(xyz, knn);
    qkv_kernel<<<dim3(256), dim3(256), 114688, stream>>>(features, w_fc1, b_fc1,
                                                         w_q, w_k, w_v, qb, kb, vb);
    main_kernel<<<dim3(1024), dim3(256), 154112, stream>>>(
        xyz, features, w_fc2, b_fc2, w_d1, b_d1, b_d2, b_g1, b_g2,
        qb, kb, vb, knn, wpk, res_out, attn_out);
}